// Round 1
// baseline (184.906 us; speedup 1.0000x reference)
//
#include <hip/hip_runtime.h>

#define BB 4096
#define TT 750
#define NS_STRIDE 768   // padded T for coalesced ns[k][t]

// ws layout (floats):
//   [0, 11*768)          ns / ens buffer
//   [11*768, 11*768+64)  partial-sum slots

// ---------------- K1: interior ns[t,k] = sum_i (a[i,t]-a[i,t+k-6])^2 ----------------
__global__ __launch_bounds__(256) void k_ns_interior(const float* __restrict__ a,
                                                     float* __restrict__ ns) {
    const int t0 = blockIdx.x * 64;          // t tile
    const int i0 = blockIdx.y * 64;          // i tile
    __shared__ float tile[64][76];           // col c -> global col t0-6+c, c in [0,74)
    __shared__ float red[4][64][11];
    const int tid = threadIdx.x;

    for (int l = tid; l < 64 * 74; l += 256) {
        int r = l / 74, c = l - r * 74;
        int gc = t0 - 6 + c;
        float v = 0.f;
        if (gc >= 0 && gc < TT) v = a[(i0 + r) * TT + gc];
        tile[r][c] = v;
    }
    __syncthreads();

    const int tl = tid & 63, ig = tid >> 6;
    const int t = t0 + tl;
    float acc[11];
#pragma unroll
    for (int k = 0; k < 11; ++k) acc[k] = 0.f;
    if (t < TT) {
        for (int r = ig; r < 64; r += 4) {
            float x = tile[r][tl + 6];
#pragma unroll
            for (int k = 0; k < 11; ++k) {
                int q = t + k - 6;
                float d = x - tile[r][tl + k];
                if (q >= 0 && q < TT) acc[k] += d * d;
            }
        }
    }
#pragma unroll
    for (int k = 0; k < 11; ++k) red[ig][tl][k] = acc[k];
    __syncthreads();

    for (int l = tid; l < 64 * 11; l += 256) {
        int tl2 = l / 11, k2 = l - tl2 * 11;
        int tt = t0 + tl2;
        int q = tt + k2 - 6;
        if (tt < TT && q >= 0 && q < TT) {
            float s = red[0][tl2][k2] + red[1][tl2][k2] + red[2][tl2][k2] + red[3][tl2][k2];
            atomicAdd(&ns[k2 * NS_STRIDE + tt], s);
        }
    }
}

// ---------------- K_edge: the 31 (t,k) pairs whose window index leaves [0,T) ----------------
__global__ __launch_bounds__(256) void k_ns_edge(const float* __restrict__ a,
                                                 float* __restrict__ ns) {
    int b = blockIdx.x;   // 0..30
    int t = 0, k = 0;
    if (b < 21) {                         // front: t+k < 6
        int idx = b;
        for (int tt = 0; tt < 6; ++tt) {
            int c = 6 - tt;
            if (idx < c) { t = tt; k = idx; break; }
            idx -= c;
        }
    } else {                              // back: t+k >= 756
        int idx = b - 21;
        for (int tt = 746; tt < 750; ++tt) {
            int c = tt - 745;             // count of k's for this t
            if (idx < c) { t = tt; k = (11 - c) + idx; break; }
            idx -= c;
        }
    }
    const int p = t + k;                  // block-uniform
    const int tid = threadIdx.x;
    float s = 0.f;
    for (int i = tid; i < BB; i += 256) {
        float x = a[i * TT + t];
        float v;
        if (p < 6) v = a[((6 * i + p) & (BB - 1)) * TT + 0];
        else       v = a[((6 * i + (p - 755)) & (BB - 1)) * TT + (TT - 1)];
        float d = x - v;
        s += d * d;
    }
    for (int off = 32; off > 0; off >>= 1) s += __shfl_down(s, off, 64);
    __shared__ float wr[4];
    if ((tid & 63) == 0) wr[tid >> 6] = s;
    __syncthreads();
    if (tid == 0) atomicAdd(&ns[k * NS_STRIDE + t], wr[0] + wr[1] + wr[2] + wr[3]);
}

// ---------------- K_exp: ns -> exp(-ns/2) ----------------
__global__ void k_exp(float* __restrict__ ns) {
    int l = blockIdx.x * 256 + threadIdx.x;
    if (l < 11 * NS_STRIDE) ns[l] = __expf(-0.5f * ns[l]);
}

// ---------------- K_main: per (i,t) loss contribution ----------------
__global__ __launch_bounds__(256) void k_main(const float* __restrict__ a,
                                              const float* __restrict__ a2,
                                              const float* __restrict__ ens,
                                              float* __restrict__ slots) {
    const int i = blockIdx.y;
    const int t = blockIdx.x * 256 + threadIdx.x;
    float partial = 0.f;
    if (t < TT) {
        const float s1 = a[i * TT + t];
        const float s2 = a2[i * TT + t];
        float mw = -1e30f;
        float d2k[11], ek[11];
#pragma unroll
        for (int k = 0; k < 11; ++k) {
            int p = t + k;
            float a4v, a3v;
            if (p < 6) {
                int r = (6 * i + p) & (BB - 1);
                a4v = a[r * TT];
                a3v = a2[r * TT];
            } else if (p < 756) {
                a4v = a[i * TT + p - 6];
                a3v = a2[i * TT + p - 6];
            } else {
                int r = (6 * i + (p - 755)) & (BB - 1);
                a4v = a[r * TT + (TT - 1)];
                a3v = a2[r * TT + (TT - 1)];
            }
            int rr = (11 * i + k) & (BB - 1);       // block-uniform row -> coalesced in t
            float tv = a[rr * TT + t];
            mw = fmaxf(mw, tv - a4v);
            d2k[k] = fabsf(s2 - a3v);
            ek[k] = ens[k * NS_STRIDE + t];
        }
        float g = mw * mw;                          // E_G = 1
        float eg = __expf(-0.5f * g);               // SIGMA = 1
        float acc = 0.f;
#pragma unroll
        for (int k = 0; k < 11; ++k) acc += fminf(ek[k], eg) * d2k[k];
        float diff = s1 - s2;
        partial = acc + 0.1f * diff * diff;         // E_THETA = 0.1
    }
    for (int off = 32; off > 0; off >>= 1) partial += __shfl_down(partial, off, 64);
    __shared__ float wred[4];
    const int lane = threadIdx.x & 63, w = threadIdx.x >> 6;
    if (lane == 0) wred[w] = partial;
    __syncthreads();
    if (threadIdx.x == 0) {
        float tot = wred[0] + wred[1] + wred[2] + wred[3];
        atomicAdd(&slots[(blockIdx.y * 3 + blockIdx.x) & 63], tot);
    }
}

// ---------------- K_final ----------------
__global__ void k_final(const float* __restrict__ slots, float* __restrict__ out) {
    float v = (threadIdx.x < 64) ? slots[threadIdx.x] : 0.f;
    for (int off = 32; off > 0; off >>= 1) v += __shfl_down(v, off, 64);
    if (threadIdx.x == 0) out[0] = v * (1.0f / BB);   // E_ALPHA = 1
}

extern "C" void kernel_launch(void* const* d_in, const int* in_sizes, int n_in,
                              void* d_out, int out_size, void* d_ws, size_t ws_size,
                              hipStream_t stream) {
    const float* a  = (const float*)d_in[0];   // actioness
    const float* a2 = (const float*)d_in[1];   // actioness_2
    float* ns    = (float*)d_ws;
    float* slots = ns + 11 * NS_STRIDE;
    float* out   = (float*)d_out;

    hipMemsetAsync(d_ws, 0, (11 * NS_STRIDE + 64) * sizeof(float), stream);
    k_ns_interior<<<dim3(12, 64), 256, 0, stream>>>(a, ns);
    k_ns_edge<<<31, 256, 0, stream>>>(a, ns);
    k_exp<<<(11 * NS_STRIDE + 255) / 256, 256, 0, stream>>>(ns);
    k_main<<<dim3(3, BB), 256, 0, stream>>>(a, a2, ns, slots);
    k_final<<<1, 64, 0, stream>>>(slots, out);
}

// Round 2
// 176.439 us; speedup vs baseline: 1.0480x; 1.0480x over previous
//
#include <hip/hip_runtime.h>

#define BB 4096
#define TT 750
#define NS_STRIDE 768   // padded T for coalesced ns[k][t]

// ws layout (floats):
//   [0, 11*768)          ns / ens buffer
//   [11*768, 11*768+64)  partial-sum slots

// ---------------- K1: interior ns[t,k] = sum_i (a[i,t]-a[i,t+k-6])^2 ----------------
__global__ __launch_bounds__(256) void k_ns_interior(const float* __restrict__ a,
                                                     float* __restrict__ ns) {
    const int t0 = blockIdx.x * 64;          // t tile
    const int i0 = blockIdx.y * 64;          // i tile
    __shared__ float tile[64][76];           // col c -> global col t0-6+c, c in [0,74)
    __shared__ float red[4][64][11];
    const int tid = threadIdx.x;

    for (int l = tid; l < 64 * 74; l += 256) {
        int r = l / 74, c = l - r * 74;
        int gc = t0 - 6 + c;
        float v = 0.f;
        if (gc >= 0 && gc < TT) v = a[(i0 + r) * TT + gc];
        tile[r][c] = v;
    }
    __syncthreads();

    const int tl = tid & 63, ig = tid >> 6;
    const int t = t0 + tl;
    float acc[11];
#pragma unroll
    for (int k = 0; k < 11; ++k) acc[k] = 0.f;
    if (t < TT) {
        for (int r = ig; r < 64; r += 4) {
            float x = tile[r][tl + 6];
#pragma unroll
            for (int k = 0; k < 11; ++k) {
                int q = t + k - 6;
                float d = x - tile[r][tl + k];
                if (q >= 0 && q < TT) acc[k] += d * d;
            }
        }
    }
#pragma unroll
    for (int k = 0; k < 11; ++k) red[ig][tl][k] = acc[k];
    __syncthreads();

    for (int l = tid; l < 64 * 11; l += 256) {
        int tl2 = l / 11, k2 = l - tl2 * 11;
        int tt = t0 + tl2;
        int q = tt + k2 - 6;
        if (tt < TT && q >= 0 && q < TT) {
            float s = red[0][tl2][k2] + red[1][tl2][k2] + red[2][tl2][k2] + red[3][tl2][k2];
            atomicAdd(&ns[k2 * NS_STRIDE + tt], s);
        }
    }
}

// ---------------- K_edge: the 31 (t,k) pairs whose window index leaves [0,T) ----------------
// grid (31, 16): y-dim slices the 4096-batch into 256-wide chunks (1 i / thread)
__global__ __launch_bounds__(256) void k_ns_edge(const float* __restrict__ a,
                                                 float* __restrict__ ns) {
    int b = blockIdx.x;   // 0..30
    int t = 0, k = 0;
    if (b < 21) {                         // front: t+k < 6
        int idx = b;
        for (int tt = 0; tt < 6; ++tt) {
            int c = 6 - tt;
            if (idx < c) { t = tt; k = idx; break; }
            idx -= c;
        }
    } else {                              // back: t+k >= 756
        int idx = b - 21;
        for (int tt = 746; tt < 750; ++tt) {
            int c = tt - 745;             // count of k's for this t
            if (idx < c) { t = tt; k = (11 - c) + idx; break; }
            idx -= c;
        }
    }
    const int p = t + k;                  // block-uniform
    const int tid = threadIdx.x;
    const int i = blockIdx.y * 256 + tid;
    float x = a[i * TT + t];
    float v;
    if (p < 6) v = a[((6 * i + p) & (BB - 1)) * TT + 0];
    else       v = a[((6 * i + (p - 755)) & (BB - 1)) * TT + (TT - 1)];
    float d = x - v;
    float s = d * d;
    for (int off = 32; off > 0; off >>= 1) s += __shfl_down(s, off, 64);
    __shared__ float wr[4];
    if ((tid & 63) == 0) wr[tid >> 6] = s;
    __syncthreads();
    if (tid == 0) atomicAdd(&ns[k * NS_STRIDE + t], wr[0] + wr[1] + wr[2] + wr[3]);
}

// ---------------- K_exp: ns -> exp(-ns/2) ----------------
__global__ void k_exp(float* __restrict__ ns) {
    int l = blockIdx.x * 256 + threadIdx.x;
    if (l < 11 * NS_STRIDE) ns[l] = __expf(-0.5f * ns[l]);
}

// ---------------- K_main: per (i,t) loss contribution ----------------
// block = (t-chunk of 256, i). Padded window rows staged in LDS once per block:
// s_a4[c] = a4pad(i, t0+c), c in [0,266); a[i,t] == s_a4[tid+6] (middle branch).
__global__ __launch_bounds__(256) void k_main(const float* __restrict__ a,
                                              const float* __restrict__ a2,
                                              const float* __restrict__ ens,
                                              float* __restrict__ slots) {
    const int i = blockIdx.y;
    const int t0 = blockIdx.x * 256;
    const int tid = threadIdx.x;
    __shared__ float s_a4[268];
    __shared__ float s_a3[268];

    for (int c = tid; c < 266; c += 256) {
        int p = t0 + c;
        float v4, v3;
        if (p < 6) {
            int r = (6 * i + p) & (BB - 1);
            v4 = a[r * TT];
            v3 = a2[r * TT];
        } else if (p < 756) {
            v4 = a[i * TT + p - 6];
            v3 = a2[i * TT + p - 6];
        } else {
            int r = (6 * i + (p - 755)) & (BB - 1);
            v4 = a[r * TT + (TT - 1)];
            v3 = a2[r * TT + (TT - 1)];
        }
        s_a4[c] = v4;
        s_a3[c] = v3;
    }
    __syncthreads();

    const int t = t0 + tid;
    float partial = 0.f;
    if (t < TT) {
        const float s1 = s_a4[tid + 6];    // a[i,t]
        const float s2 = s_a3[tid + 6];    // a2[i,t]
        float mw = -1e30f;
        float acc_d[11], acc_e[11];
#pragma unroll
        for (int k = 0; k < 11; ++k) {
            float a4v = s_a4[tid + k];
            float a3v = s_a3[tid + k];
            int rr = (11 * i + k) & (BB - 1);       // block-uniform row -> coalesced in t
            float tv = a[rr * TT + t];
            mw = fmaxf(mw, tv - a4v);
            acc_d[k] = fabsf(s2 - a3v);
            acc_e[k] = ens[k * NS_STRIDE + t];
        }
        float g = mw * mw;                          // E_G = 1
        float eg = __expf(-0.5f * g);               // SIGMA = 1
        float acc = 0.f;
#pragma unroll
        for (int k = 0; k < 11; ++k) acc += fminf(acc_e[k], eg) * acc_d[k];
        float diff = s1 - s2;
        partial = acc + 0.1f * diff * diff;         // E_THETA = 0.1
    }
    for (int off = 32; off > 0; off >>= 1) partial += __shfl_down(partial, off, 64);
    __shared__ float wred[4];
    const int lane = tid & 63, w = tid >> 6;
    if (lane == 0) wred[w] = partial;
    __syncthreads();
    if (tid == 0) {
        float tot = wred[0] + wred[1] + wred[2] + wred[3];
        atomicAdd(&slots[(blockIdx.y * 3 + blockIdx.x) & 63], tot);
    }
}

// ---------------- K_final ----------------
__global__ void k_final(const float* __restrict__ slots, float* __restrict__ out) {
    float v = (threadIdx.x < 64) ? slots[threadIdx.x] : 0.f;
    for (int off = 32; off > 0; off >>= 1) v += __shfl_down(v, off, 64);
    if (threadIdx.x == 0) out[0] = v * (1.0f / BB);   // E_ALPHA = 1
}

extern "C" void kernel_launch(void* const* d_in, const int* in_sizes, int n_in,
                              void* d_out, int out_size, void* d_ws, size_t ws_size,
                              hipStream_t stream) {
    const float* a  = (const float*)d_in[0];   // actioness
    const float* a2 = (const float*)d_in[1];   // actioness_2
    float* ns    = (float*)d_ws;
    float* slots = ns + 11 * NS_STRIDE;
    float* out   = (float*)d_out;

    hipMemsetAsync(d_ws, 0, (11 * NS_STRIDE + 64) * sizeof(float), stream);
    k_ns_interior<<<dim3(12, 64), 256, 0, stream>>>(a, ns);
    k_ns_edge<<<dim3(31, 16), 256, 0, stream>>>(a, ns);
    k_exp<<<(11 * NS_STRIDE + 255) / 256, 256, 0, stream>>>(ns);
    k_main<<<dim3(3, BB), 256, 0, stream>>>(a, a2, ns, slots);
    k_final<<<1, 64, 0, stream>>>(slots, out);
}

// Round 3
// 176.397 us; speedup vs baseline: 1.0482x; 1.0002x over previous
//
#include <hip/hip_runtime.h>

#define BB 4096
#define TT 750
#define NS_STRIDE 768   // padded T for coalesced ns[k][t]

// ws layout (floats):
//   [0, 11*768)               ns / ens buffer
//   [11*768, 11*768+64)       partial-sum slots
//   [11*768+64]               flag: any ens > 0 (int)

// ---------------- K1: interior ns[t,k] = sum_i (a[i,t]-a[i,t+k-6])^2 ----------------
__global__ __launch_bounds__(256) void k_ns_interior(const float* __restrict__ a,
                                                     float* __restrict__ ns) {
    const int t0 = blockIdx.x * 64;          // t tile
    const int i0 = blockIdx.y * 64;          // i tile
    __shared__ float tile[64][76];           // col c -> global col t0-6+c, c in [0,74)
    __shared__ float red[4][64][11];
    const int tid = threadIdx.x;

    for (int l = tid; l < 64 * 74; l += 256) {
        int r = l / 74, c = l - r * 74;
        int gc = t0 - 6 + c;
        float v = 0.f;
        if (gc >= 0 && gc < TT) v = a[(i0 + r) * TT + gc];
        tile[r][c] = v;
    }
    __syncthreads();

    const int tl = tid & 63, ig = tid >> 6;
    float acc[11];
#pragma unroll
    for (int k = 0; k < 11; ++k) acc[k] = 0.f;

    if (blockIdx.x >= 1 && blockIdx.x <= 10) {
        // interior: t in [64,704), q = t+k-6 in [58,708) -- always valid, no guards
        for (int r = ig; r < 64; r += 4) {
            float x = tile[r][tl + 6];
#pragma unroll
            for (int k = 0; k < 11; ++k) {
                float d = x - tile[r][tl + k];
                acc[k] += d * d;
            }
        }
    } else {
        const int t = t0 + tl;
        if (t < TT) {
            for (int r = ig; r < 64; r += 4) {
                float x = tile[r][tl + 6];
#pragma unroll
                for (int k = 0; k < 11; ++k) {
                    int q = t + k - 6;
                    float d = x - tile[r][tl + k];
                    if (q >= 0 && q < TT) acc[k] += d * d;
                }
            }
        }
    }
#pragma unroll
    for (int k = 0; k < 11; ++k) red[ig][tl][k] = acc[k];
    __syncthreads();

    for (int l = tid; l < 64 * 11; l += 256) {
        int tl2 = l / 11, k2 = l - tl2 * 11;
        int tt = t0 + tl2;
        int q = tt + k2 - 6;
        if (tt < TT && q >= 0 && q < TT) {
            float s = red[0][tl2][k2] + red[1][tl2][k2] + red[2][tl2][k2] + red[3][tl2][k2];
            atomicAdd(&ns[k2 * NS_STRIDE + tt], s);
        }
    }
}

// ---------------- K_edge: the 31 (t,k) pairs whose window index leaves [0,T) ----------------
// grid (31, 16): y-dim slices the 4096-batch into 256-wide chunks (1 i / thread)
__global__ __launch_bounds__(256) void k_ns_edge(const float* __restrict__ a,
                                                 float* __restrict__ ns) {
    int b = blockIdx.x;   // 0..30
    int t = 0, k = 0;
    if (b < 21) {                         // front: t+k < 6
        int idx = b;
        for (int tt = 0; tt < 6; ++tt) {
            int c = 6 - tt;
            if (idx < c) { t = tt; k = idx; break; }
            idx -= c;
        }
    } else {                              // back: t+k >= 756
        int idx = b - 21;
        for (int tt = 746; tt < 750; ++tt) {
            int c = tt - 745;             // count of k's for this t
            if (idx < c) { t = tt; k = (11 - c) + idx; break; }
            idx -= c;
        }
    }
    const int p = t + k;                  // block-uniform
    const int tid = threadIdx.x;
    const int i = blockIdx.y * 256 + tid;
    float x = a[i * TT + t];
    float v;
    if (p < 6) v = a[((6 * i + p) & (BB - 1)) * TT + 0];
    else       v = a[((6 * i + (p - 755)) & (BB - 1)) * TT + (TT - 1)];
    float d = x - v;
    float s = d * d;
    for (int off = 32; off > 0; off >>= 1) s += __shfl_down(s, off, 64);
    __shared__ float wr[4];
    if ((tid & 63) == 0) wr[tid >> 6] = s;
    __syncthreads();
    if (tid == 0) atomicAdd(&ns[k * NS_STRIDE + t], wr[0] + wr[1] + wr[2] + wr[3]);
}

// ---------------- K_exp: ns -> exp(-ns/2); flag = any(ens > 0) over valid t ----------------
__global__ void k_exp(float* __restrict__ ns, int* __restrict__ flag) {
    int l = blockIdx.x * 256 + threadIdx.x;
    if (l < 11 * NS_STRIDE) {
        float e = __expf(-0.5f * ns[l]);
        ns[l] = e;
        int k = l / NS_STRIDE;
        int t = l - k * NS_STRIDE;
        if (t < TT && e > 0.f) atomicOr(flag, 1);   // padded tail excluded (memset-0 -> e=1)
    }
}

// ---------------- K_main: per (i,t) loss contribution ----------------
// If flag==0: every ens[t,k]==0 so min(ens,eg)*d2 == 0 for all k -- only the reg term
// survives. This is a data-driven (input-general) skip, block-uniform branch.
__global__ __launch_bounds__(256) void k_main(const float* __restrict__ a,
                                              const float* __restrict__ a2,
                                              const float* __restrict__ ens,
                                              const int* __restrict__ flag,
                                              float* __restrict__ slots) {
    const int i = blockIdx.y;
    const int t0 = blockIdx.x * 256;
    const int tid = threadIdx.x;
    const int t = t0 + tid;
    float partial = 0.f;

    if (flag[0] == 0) {
        // fast path: windowed term identically zero
        if (t < TT) {
            float d = a[i * TT + t] - a2[i * TT + t];
            partial = 0.1f * d * d;                 // E_THETA = 0.1
        }
    } else {
        // general path (verified round-1 code)
        __shared__ float s_a4[268];
        __shared__ float s_a3[268];
        for (int c = tid; c < 266; c += 256) {
            int p = t0 + c;
            float v4, v3;
            if (p < 6) {
                int r = (6 * i + p) & (BB - 1);
                v4 = a[r * TT];
                v3 = a2[r * TT];
            } else if (p < 756) {
                v4 = a[i * TT + p - 6];
                v3 = a2[i * TT + p - 6];
            } else {
                int r = (6 * i + (p - 755)) & (BB - 1);
                v4 = a[r * TT + (TT - 1)];
                v3 = a2[r * TT + (TT - 1)];
            }
            s_a4[c] = v4;
            s_a3[c] = v3;
        }
        __syncthreads();
        if (t < TT) {
            const float s1 = s_a4[tid + 6];    // a[i,t]
            const float s2 = s_a3[tid + 6];    // a2[i,t]
            float mw = -1e30f;
            float acc_d[11], acc_e[11];
#pragma unroll
            for (int k = 0; k < 11; ++k) {
                float a4v = s_a4[tid + k];
                float a3v = s_a3[tid + k];
                int rr = (11 * i + k) & (BB - 1);   // block-uniform row -> coalesced in t
                float tv = a[rr * TT + t];
                mw = fmaxf(mw, tv - a4v);
                acc_d[k] = fabsf(s2 - a3v);
                acc_e[k] = ens[k * NS_STRIDE + t];
            }
            float g = mw * mw;                      // E_G = 1
            float eg = __expf(-0.5f * g);           // SIGMA = 1
            float acc = 0.f;
#pragma unroll
            for (int k = 0; k < 11; ++k) acc += fminf(acc_e[k], eg) * acc_d[k];
            float diff = s1 - s2;
            partial = acc + 0.1f * diff * diff;
        }
    }

    for (int off = 32; off > 0; off >>= 1) partial += __shfl_down(partial, off, 64);
    __shared__ float wred[4];
    const int lane = tid & 63, w = tid >> 6;
    if (lane == 0) wred[w] = partial;
    __syncthreads();
    if (tid == 0) {
        float tot = wred[0] + wred[1] + wred[2] + wred[3];
        atomicAdd(&slots[(blockIdx.y * 3 + blockIdx.x) & 63], tot);
    }
}

// ---------------- K_final ----------------
__global__ void k_final(const float* __restrict__ slots, float* __restrict__ out) {
    float v = (threadIdx.x < 64) ? slots[threadIdx.x] : 0.f;
    for (int off = 32; off > 0; off >>= 1) v += __shfl_down(v, off, 64);
    if (threadIdx.x == 0) out[0] = v * (1.0f / BB);   // E_ALPHA = 1
}

extern "C" void kernel_launch(void* const* d_in, const int* in_sizes, int n_in,
                              void* d_out, int out_size, void* d_ws, size_t ws_size,
                              hipStream_t stream) {
    const float* a  = (const float*)d_in[0];   // actioness
    const float* a2 = (const float*)d_in[1];   // actioness_2
    float* ns    = (float*)d_ws;
    float* slots = ns + 11 * NS_STRIDE;
    int*   flag  = (int*)(slots + 64);
    float* out   = (float*)d_out;

    hipMemsetAsync(d_ws, 0, (11 * NS_STRIDE + 64 + 1) * sizeof(float), stream);
    k_ns_interior<<<dim3(12, 64), 256, 0, stream>>>(a, ns);
    k_ns_edge<<<dim3(31, 16), 256, 0, stream>>>(a, ns);
    k_exp<<<(11 * NS_STRIDE + 255) / 256, 256, 0, stream>>>(ns, flag);
    k_main<<<dim3(3, BB), 256, 0, stream>>>(a, a2, ns, flag, slots);
    k_final<<<1, 64, 0, stream>>>(slots, out);
}

// Round 4
// 124.583 us; speedup vs baseline: 1.4842x; 1.4159x over previous
//
#include <hip/hip_runtime.h>

#define BB 4096
#define TT 750
#define NS_STRIDE 768

// ws layout (floats):
//   ns_p   [0, 768*704)                      per-block interior partials
//   edge_c [540672, 540672+124)              edge-pair partials (31 pairs x 4 chunks)
//   ens    [540796, 540796+8448)             exp(-ns/2), layout [k][t] stride 768
//   flags  [549244, 549244+33)  (as int)     per-reduce-block "any ens>0"
//   slots  [549277, 549277+768)              per-k_main-block partial sums

#define NSP_OFF   0
#define EDGE_OFF  (768 * 704)
#define ENS_OFF   (EDGE_OFF + 124)
#define FLAG_OFF  (ENS_OFF + 11 * NS_STRIDE)
#define SLOT_OFF  (FLAG_OFF + 33)

// ---------------- K1 (fused): interior ns partials + edge pairs, NO atomics ----------------
__global__ __launch_bounds__(256) void k_ns_fused(const float* __restrict__ a,
                                                  float* __restrict__ ns_p,
                                                  float* __restrict__ edge_c) {
    __shared__ float tile[64][76];
    __shared__ float red[4][64][11];
    const int b = blockIdx.x;
    const int tid = threadIdx.x;

    if (b < 768) {
        const int x = b % 12, y = b / 12;
        const int t0 = x * 64, i0 = y * 64;

        for (int l = tid; l < 64 * 74; l += 256) {
            int r = l / 74, c = l - r * 74;
            int gc = t0 - 6 + c;
            float v = 0.f;
            if (gc >= 0 && gc < TT) v = a[(i0 + r) * TT + gc];
            tile[r][c] = v;
        }
        __syncthreads();

        const int tl = tid & 63, ig = tid >> 6;
        float acc[11];
#pragma unroll
        for (int k = 0; k < 11; ++k) acc[k] = 0.f;

        if (x >= 1 && x <= 10) {
            // interior tiles: q = t+k-6 always in range, no guards
            for (int r = ig; r < 64; r += 4) {
                float xx = tile[r][tl + 6];
#pragma unroll
                for (int k = 0; k < 11; ++k) {
                    float d = xx - tile[r][tl + k];
                    acc[k] += d * d;
                }
            }
        } else {
            const int t = t0 + tl;
            if (t < TT) {
                for (int r = ig; r < 64; r += 4) {
                    float xx = tile[r][tl + 6];
#pragma unroll
                    for (int k = 0; k < 11; ++k) {
                        int q = t + k - 6;
                        float d = xx - tile[r][tl + k];
                        if (q >= 0 && q < TT) acc[k] += d * d;
                    }
                }
            }
        }
#pragma unroll
        for (int k = 0; k < 11; ++k) red[ig][tl][k] = acc[k];
        __syncthreads();

        // plain coalesced store of this block's 704 partials
        for (int l = tid; l < 64 * 11; l += 256) {
            int tl2 = l / 11, k2 = l - tl2 * 11;
            ns_p[b * 704 + l] =
                red[0][tl2][k2] + red[1][tl2][k2] + red[2][tl2][k2] + red[3][tl2][k2];
        }
    } else {
        // edge blocks: eb in [0,124): pair q = eb%31, i-chunk ch = eb/31
        const int eb = b - 768;
        const int q = eb % 31;
        const int ch = eb / 31;
        int t = 0, k = 0;
        if (q < 21) {                       // front: t+k < 6, t-major ordering
            int idx = q;
            for (int tt = 0; tt < 6; ++tt) {
                int c = 6 - tt;
                if (idx < c) { t = tt; k = idx; break; }
                idx -= c;
            }
        } else {                            // back: t+k >= 756
            int idx = q - 21;
            for (int tt = 746; tt < 750; ++tt) {
                int c = tt - 745;
                if (idx < c) { t = tt; k = (11 - c) + idx; break; }
                idx -= c;
            }
        }
        const int p = t + k;                // block-uniform
        float s = 0.f;
        int i = ch * 1024 + tid;
#pragma unroll
        for (int it = 0; it < 4; ++it, i += 256) {
            float xv = a[i * TT + t];
            float v = (p < 6) ? a[((6 * i + p) & (BB - 1)) * TT]
                              : a[((6 * i + (p - 755)) & (BB - 1)) * TT + (TT - 1)];
            float d = xv - v;
            s += d * d;
        }
        for (int off = 32; off > 0; off >>= 1) s += __shfl_down(s, off, 64);
        if ((tid & 63) == 0) red[0][0][tid >> 6] = s;
        __syncthreads();
        if (tid == 0)
            edge_c[q * 4 + ch] = red[0][0][0] + red[0][0][1] + red[0][0][2] + red[0][0][3];
    }
}

// ---------------- K2: reduce partials, add edge, exp, per-block flag ----------------
__global__ __launch_bounds__(256) void k_reduce_exp(const float* __restrict__ ns_p,
                                                    const float* __restrict__ edge_c,
                                                    float* __restrict__ ens,
                                                    int* __restrict__ flags) {
    const int l = blockIdx.x * 256 + threadIdx.x;     // 33*256 = 8448
    const int k = l / NS_STRIDE;
    const int t = l - k * NS_STRIDE;
    float e = 0.f;
    if (t < TT) {
        const int x = t >> 6, tl = t & 63;
        const int off = x * 704 + tl * 11 + k;
        float s = 0.f;
        for (int y = 0; y < 64; ++y) s += ns_p[y * 8448 + off];
        const int p = t + k;
        if (p < 6 || p >= 756) {
            int idx = (p < 6) ? (t * 6 - t * (t - 1) / 2 + k)
                              : (21 + (t - 746) * (t - 745) / 2 + (k - (756 - t)));
            s += edge_c[idx * 4 + 0] + edge_c[idx * 4 + 1] +
                 edge_c[idx * 4 + 2] + edge_c[idx * 4 + 3];
        }
        e = __expf(-0.5f * s);
    }
    ens[l] = e;

    // block-level "any e > 0" flag (plain store, no memset/atomic needed)
    unsigned long long anyb = __ballot(e > 0.f);
    __shared__ int wf[4];
    const int lane = threadIdx.x & 63, w = threadIdx.x >> 6;
    if (lane == 0) wf[w] = (anyb != 0ull);
    __syncthreads();
    if (threadIdx.x == 0) flags[blockIdx.x] = wf[0] | wf[1] | wf[2] | wf[3];
}

// ---------------- K3: main loss, 16 i's per block, one plain store per block ----------------
__global__ __launch_bounds__(256) void k_main(const float* __restrict__ a,
                                              const float* __restrict__ a2,
                                              const float* __restrict__ ens,
                                              const int* __restrict__ flags,
                                              float* __restrict__ slots) {
    const int x = blockIdx.x;           // t-chunk 0..2
    const int y = blockIdx.y;           // i-group 0..255
    const int tid = threadIdx.x;
    const int t0 = x * 256;
    const int t = t0 + tid;

    int flag = 0;
    for (int j = 0; j < 33; ++j) flag |= flags[j];   // uniform, L2-cached

    float partial = 0.f;
    if (flag == 0) {
        // windowed term identically zero (all ens == 0): only the reg term survives
        if (t < TT) {
            float s = 0.f;
#pragma unroll
            for (int ii = 0; ii < 16; ++ii) {
                int i = y * 16 + ii;
                float d = a[i * TT + t] - a2[i * TT + t];
                s += d * d;
            }
            partial = 0.1f * s;                       // E_THETA
        }
    } else {
        __shared__ float s_a4[268];
        __shared__ float s_a3[268];
        for (int ii = 0; ii < 16; ++ii) {
            const int i = y * 16 + ii;
            __syncthreads();            // protect LDS reuse across iterations
            for (int c = tid; c < 266; c += 256) {
                int p = t0 + c;
                float v4, v3;
                if (p < 6) {
                    int r = (6 * i + p) & (BB - 1);
                    v4 = a[r * TT];
                    v3 = a2[r * TT];
                } else if (p < 756) {
                    v4 = a[i * TT + p - 6];
                    v3 = a2[i * TT + p - 6];
                } else {
                    int r = (6 * i + (p - 755)) & (BB - 1);
                    v4 = a[r * TT + (TT - 1)];
                    v3 = a2[r * TT + (TT - 1)];
                }
                s_a4[c] = v4;
                s_a3[c] = v3;
            }
            __syncthreads();
            if (t < TT) {
                const float s1 = s_a4[tid + 6];
                const float s2 = s_a3[tid + 6];
                float mw = -1e30f;
                float acc_d[11], acc_e[11];
#pragma unroll
                for (int k = 0; k < 11; ++k) {
                    float a4v = s_a4[tid + k];
                    float a3v = s_a3[tid + k];
                    int rr = (11 * i + k) & (BB - 1);
                    float tv = a[rr * TT + t];
                    mw = fmaxf(mw, tv - a4v);
                    acc_d[k] = fabsf(s2 - a3v);
                    acc_e[k] = ens[k * NS_STRIDE + t];
                }
                float g = mw * mw;                    // E_G
                float eg = __expf(-0.5f * g);         // SIGMA
                float acc = 0.f;
#pragma unroll
                for (int k = 0; k < 11; ++k) acc += fminf(acc_e[k], eg) * acc_d[k];
                float diff = s1 - s2;
                partial += acc + 0.1f * diff * diff;
            }
        }
    }

    for (int off = 32; off > 0; off >>= 1) partial += __shfl_down(partial, off, 64);
    __shared__ float wred[4];
    const int lane = tid & 63, w = tid >> 6;
    if (lane == 0) wred[w] = partial;
    __syncthreads();
    if (tid == 0)
        slots[y * 3 + x] = wred[0] + wred[1] + wred[2] + wred[3];   // plain store
}

// ---------------- K4: final reduce of 768 slots ----------------
__global__ __launch_bounds__(256) void k_final(const float* __restrict__ slots,
                                               float* __restrict__ out) {
    const int tid = threadIdx.x;
    float v = slots[tid] + slots[tid + 256] + slots[tid + 512];
    for (int off = 32; off > 0; off >>= 1) v += __shfl_down(v, off, 64);
    __shared__ float wred[4];
    if ((tid & 63) == 0) wred[tid >> 6] = v;
    __syncthreads();
    if (tid == 0)
        out[0] = (wred[0] + wred[1] + wred[2] + wred[3]) * (1.0f / BB);  // E_ALPHA
}

extern "C" void kernel_launch(void* const* d_in, const int* in_sizes, int n_in,
                              void* d_out, int out_size, void* d_ws, size_t ws_size,
                              hipStream_t stream) {
    const float* a  = (const float*)d_in[0];   // actioness
    const float* a2 = (const float*)d_in[1];   // actioness_2
    float* ws     = (float*)d_ws;
    float* ns_p   = ws + NSP_OFF;
    float* edge_c = ws + EDGE_OFF;
    float* ens    = ws + ENS_OFF;
    int*   flags  = (int*)(ws + FLAG_OFF);
    float* slots  = ws + SLOT_OFF;
    float* out    = (float*)d_out;

    k_ns_fused<<<768 + 124, 256, 0, stream>>>(a, ns_p, edge_c);
    k_reduce_exp<<<33, 256, 0, stream>>>(ns_p, edge_c, ens, flags);
    k_main<<<dim3(3, 256), 256, 0, stream>>>(a, a2, ens, flags, slots);
    k_final<<<1, 256, 0, stream>>>(slots, out);
}